// Round 20
// baseline (163.535 us; speedup 1.0000x reference)
//
#include <hip/hip_runtime.h>

#define MODES 10
#define NPH 5
#define DEPTH 10
#define NST5 2002
#define BATCH 4096
#define KSPLIT 16
#define KCHUNK 126

// Factorial-normalized SLOS: b[t] = sum_j U[j,i] b[parent];
// probs[t] = c2[t] * |b5[t]|^2, c2[t] = prod_j t_j! (exact small ints).
// COMPACT tables (no padding slots; 10010 edges vs 13650 padded):
//   per level, targets sorted by in-degree d (bucketed, wave-uniform);
//   g_meta[pos] = orig_t | (d<<11) | (rel_edge_off<<14)
//   g_edges[..] = parent_idx | (j<<12), j-ascending per target (fixed order
//   => per-target fmaf sequence identical to padded version => bit-identical).
__device__ unsigned g_meta[3002];
__device__ unsigned g_edges[10010];
__device__ float g_c2[NST5];
__device__ float2 g_M[MODES][NPH];       // batch-independent mesh matrix cols 0..4
__device__ float g_probs[(size_t)BATCH * NST5];
__device__ float g_part[(size_t)KSPLIT * BATCH * 64];

// ---------- combinatorics ----------
// count(m, n) = C(n+m-1, m-1), m in [1,10], n in [0,5] -> exact constant LUT
// (i64 mul/div loop here previously made table-gen take 134 us: soft i64 div).
__device__ __forceinline__ int d_count(int m, int n) {
    static const unsigned short C[11][6] = {
        {0, 0, 0, 0, 0, 0},
        {1, 1, 1, 1, 1, 1},
        {1, 2, 3, 4, 5, 6},
        {1, 3, 6, 10, 15, 21},
        {1, 4, 10, 20, 35, 56},
        {1, 5, 15, 35, 70, 126},
        {1, 6, 21, 56, 126, 252},
        {1, 7, 28, 84, 210, 462},
        {1, 8, 36, 120, 330, 792},
        {1, 9, 45, 165, 495, 1287},
        {1, 10, 55, 220, 715, 2002},
    };
    return C[m][n];
}

__device__ void d_unrank(int r, int n, int* s) {
    for (int p = 0; p < MODES; p++) {
        int mm = MODES - p;
        if (mm == 1) { s[p] = n; return; }
        int k = n;
        for (; k >= 0; k--) {
            int c = d_count(mm - 1, n - k);
            if (r < c) break;
            r -= c;
        }
        s[p] = k; n -= k;
    }
}

__device__ int d_rank(const int* s, int n) {
    int r = 0;
    for (int p = 0; p < MODES && n > 0; p++) {
        int mm = MODES - p;
        if (mm == 1) break;
        for (int k = n; k > s[p]; k--) r += d_count(mm - 1, n - k);
        n -= s[p];
    }
    return r;
}

// ---------- setup: block 0 builds compact tables, block 1 builds g_M ----------
__global__ __launch_bounds__(1024)
void k_setup(const float* __restrict__ theta) {
    const int tid = threadIdx.x;

    if (blockIdx.x == 1) {
        // mesh matrix M = BS9 D9 ... BS1 D1 BS0 (batch-independent; cols 0..4)
        __shared__ float2 Ush[MODES][NPH];
        const int r = tid / 5, c = tid % 5;
        const bool act = (tid < 50);
        float2 val = make_float2((act && r == c) ? 1.f : 0.f, 0.f);
        for (int l = 0; l < DEPTH; l++) {
            if (act && l > 0) {
                float ang = theta[(l - 1) * MODES + r];
                float s_, c_; sincosf(ang, &s_, &c_);
                float nx = val.x * c_ - val.y * s_;
                float ny = val.x * s_ + val.y * c_;
                val = make_float2(nx, ny);
            }
            if (act) Ush[r][c] = val;
            __syncthreads();
            float2 nv = val;
            if (act) {
                int o = l & 1;
                int lo = r - o;
                int partner = o + (lo ^ 1);
                if (lo >= 0 && partner < MODES) {
                    float2 pb = Ush[partner][c];
                    const float inv = 0.70710678118654752f;
                    nv.x = inv * (val.x - pb.y);
                    nv.y = inv * (val.y + pb.x);
                }
            }
            __syncthreads();
            val = nv;
        }
        if (act) g_M[r][c] = val;
        return;
    }

    // ---- block 0: compact transition tables ----
    __shared__ int cnt[5][5], baseP[5][5], baseE[5][5], cur[5][5];
    const int sizes[5] = {10, 55, 220, 715, 2002};
    const int mb[5]    = {0, 10, 65, 285, 1000};
    const int eb[5]    = {0, 10, 110, 660, 2860};

    if (tid < 25) cnt[tid / 5][tid % 5] = 0;
    __syncthreads();

    // phase 1: in-degree histogram per (level, d)
    for (int id = tid; id < 3002; id += 1024) {
        int k = 0, t = id;
        while (k < 5 && t >= sizes[k]) { t -= sizes[k]; k++; }
        int s[10];
        d_unrank(t, k + 1, s);
        int d = 0;
        for (int j = 0; j < MODES; j++) d += (s[j] > 0);
        atomicAdd(&cnt[k][d - 1], 1);
    }
    __syncthreads();
    if (tid == 0) {
        for (int k = 0; k < 5; k++) {
            int p = mb[k], e = eb[k];
            for (int d = 1; d <= 5; d++) {
                baseP[k][d - 1] = p; baseE[k][d - 1] = e;
                p += cnt[k][d - 1]; e += cnt[k][d - 1] * d;
            }
        }
    }
    if (tid < 25) cur[tid / 5][tid % 5] = 0;
    __syncthreads();

    // phase 2: emit (bucket position via atomic; per-target output independent
    // of position => deterministic results)
    for (int id = tid; id < 3002; id += 1024) {
        int k = 0, t = id;
        while (k < 5 && t >= sizes[k]) { t -= sizes[k]; k++; }
        int s[10];
        d_unrank(t, k + 1, s);
        int d = 0;
        for (int j = 0; j < MODES; j++) d += (s[j] > 0);
        int slot = atomicAdd(&cur[k][d - 1], 1);
        int pos = baseP[k][d - 1] + slot;
        int eo  = baseE[k][d - 1] + slot * d;
        g_meta[pos] = (unsigned)t | ((unsigned)d << 11) |
                      ((unsigned)(eo - eb[k]) << 14);
        int w = 0;
        for (int j = 0; j < MODES; j++) {
            if (s[j] > 0) {
                s[j]--;
                int p = d_rank(s, k);
                s[j]++;
                g_edges[eo + w] = (unsigned)p | ((unsigned)j << 12);
                w++;
            }
        }
        if (k == 4) {
            const float fact[6] = {1.f, 1.f, 2.f, 6.f, 24.f, 120.f};
            float c2 = 1.f;
            for (int j = 0; j < MODES; j++) c2 *= fact[s[j]];
            g_c2[t] = c2;
        }
    }
}

// ---------- SLOS level step, compact edges, 4 batch elems packed ----------
__device__ __forceinline__ void slos_lvl(const float4 (*__restrict__ src)[2],
                                         float4 (*__restrict__ dst)[2],
                                         const unsigned* __restrict__ meta,
                                         const unsigned* __restrict__ edges,
                                         int N, int tid,
                                         const float4 (*Ua)[NPH],
                                         const float4 (*Ub)[NPH], int k) {
    for (int pos = tid; pos < N; pos += 256) {
        unsigned m = meta[pos];
        int t = m & 0x7FF;
        int d = (m >> 11) & 0x7;
        const unsigned* ee = edges + (m >> 14);
        float ax0 = 0.f, ay0 = 0.f, ax1 = 0.f, ay1 = 0.f;
        float ax2 = 0.f, ay2 = 0.f, ax3 = 0.f, ay3 = 0.f;
        for (int sl = 0; sl < d; sl++) {
            unsigned e = ee[sl];
            int idx = e & 0xFFF;
            int j = (e >> 12) & 0xF;
            float4 a01 = src[idx][0];
            float4 a23 = src[idx][1];
            float4 u01 = Ua[j][k];
            float4 u23 = Ub[j][k];
            ax0 = fmaf(u01.x, a01.x, ax0); ax0 = fmaf(-u01.y, a01.y, ax0);
            ay0 = fmaf(u01.x, a01.y, ay0); ay0 = fmaf( u01.y, a01.x, ay0);
            ax1 = fmaf(u01.z, a01.z, ax1); ax1 = fmaf(-u01.w, a01.w, ax1);
            ay1 = fmaf(u01.z, a01.w, ay1); ay1 = fmaf( u01.w, a01.z, ay1);
            ax2 = fmaf(u23.x, a23.x, ax2); ax2 = fmaf(-u23.y, a23.y, ax2);
            ay2 = fmaf(u23.x, a23.y, ay2); ay2 = fmaf( u23.y, a23.x, ay2);
            ax3 = fmaf(u23.z, a23.z, ax3); ax3 = fmaf(-u23.w, a23.w, ax3);
            ay3 = fmaf(u23.z, a23.w, ay3); ay3 = fmaf( u23.w, a23.z, ay3);
        }
        dst[t][0] = make_float4(ax0, ay0, ax1, ay1);
        dst[t][1] = make_float4(ax2, ay2, ax3, ay3);
    }
    __syncthreads();
}

// ---------- SLOS, 4 batch elements per block ----------
__global__ __launch_bounds__(256)
void k_slos(const float* __restrict__ x) {
    __shared__ float4 Ua[MODES][NPH];    // (b0.re, b0.im, b1.re, b1.im)
    __shared__ float4 Ub[MODES][NPH];    // (b2.re, b2.im, b3.re, b3.im)
    __shared__ float4 ampA[715][2];
    __shared__ float4 ampB[220][2];

    const int b0 = blockIdx.x * 4;
    const int tid = threadIdx.x;
    const int r = tid / 5, c = tid % 5;

    if (tid < 50) {
        const float TP = 6.28318530717958647692f;
        float s0, c0, s1, c1, s2, c2, s3, c3;
        sincosf(TP * x[(b0 + 0) * MODES + c], &s0, &c0);
        sincosf(TP * x[(b0 + 1) * MODES + c], &s1, &c1);
        sincosf(TP * x[(b0 + 2) * MODES + c], &s2, &c2);
        sincosf(TP * x[(b0 + 3) * MODES + c], &s3, &c3);
        float2 m = g_M[r][c];
        Ua[r][c] = make_float4(m.x * c0 - m.y * s0, m.x * s0 + m.y * c0,
                               m.x * c1 - m.y * s1, m.x * s1 + m.y * c1);
        Ub[r][c] = make_float4(m.x * c2 - m.y * s2, m.x * s2 + m.y * c2,
                               m.x * c3 - m.y * s3, m.x * s3 + m.y * c3);
    }
    if (tid == 0) {
        ampA[0][0] = make_float4(1.f, 0.f, 1.f, 0.f);
        ampA[0][1] = make_float4(1.f, 0.f, 1.f, 0.f);
    }
    __syncthreads();

    slos_lvl(ampA, ampB, g_meta + 0,    g_edges + 0,    10,  tid, Ua, Ub, 0);
    slos_lvl(ampB, ampA, g_meta + 10,   g_edges + 10,   55,  tid, Ua, Ub, 1);
    slos_lvl(ampA, ampB, g_meta + 65,   g_edges + 110,  220, tid, Ua, Ub, 2);
    slos_lvl(ampB, ampA, g_meta + 285,  g_edges + 660,  715, tid, Ua, Ub, 3);

    // level 4 fused with c2 * |.|^2 -> global (no LDS round-trip)
    float* po0 = g_probs + (size_t)b0 * NST5;
    float* po1 = po0 + NST5;
    float* po2 = po1 + NST5;
    float* po3 = po2 + NST5;
    const unsigned* meta = g_meta + 1000;
    const unsigned* edges = g_edges + 2860;
    for (int pos = tid; pos < NST5; pos += 256) {
        unsigned m = meta[pos];
        int t = m & 0x7FF;
        int d = (m >> 11) & 0x7;
        const unsigned* ee = edges + (m >> 14);
        float ax0 = 0.f, ay0 = 0.f, ax1 = 0.f, ay1 = 0.f;
        float ax2 = 0.f, ay2 = 0.f, ax3 = 0.f, ay3 = 0.f;
        for (int sl = 0; sl < d; sl++) {
            unsigned e = ee[sl];
            int idx = e & 0xFFF;
            int j = (e >> 12) & 0xF;
            float4 a01 = ampA[idx][0];
            float4 a23 = ampA[idx][1];
            float4 u01 = Ua[j][4];
            float4 u23 = Ub[j][4];
            ax0 = fmaf(u01.x, a01.x, ax0); ax0 = fmaf(-u01.y, a01.y, ax0);
            ay0 = fmaf(u01.x, a01.y, ay0); ay0 = fmaf( u01.y, a01.x, ay0);
            ax1 = fmaf(u01.z, a01.z, ax1); ax1 = fmaf(-u01.w, a01.w, ax1);
            ay1 = fmaf(u01.z, a01.w, ay1); ay1 = fmaf( u01.w, a01.z, ay1);
            ax2 = fmaf(u23.x, a23.x, ax2); ax2 = fmaf(-u23.y, a23.y, ax2);
            ay2 = fmaf(u23.x, a23.y, ay2); ay2 = fmaf( u23.y, a23.x, ay2);
            ax3 = fmaf(u23.z, a23.z, ax3); ax3 = fmaf(-u23.w, a23.w, ax3);
            ay3 = fmaf(u23.z, a23.w, ay3); ay3 = fmaf( u23.w, a23.z, ay3);
        }
        float c2v = g_c2[t];
        po0[t] = c2v * (ax0 * ax0 + ay0 * ay0);
        po1[t] = c2v * (ax1 * ax1 + ay1 * ay1);
        po2[t] = c2v * (ax2 * ax2 + ay2 * ay2);
        po3[t] = c2v * (ax3 * ax3 + ay3 * ay3);
    }
}

// ---------- GEMM: g_part[kc] = P[64-row tile] x W  (LDS-tiled, K split x16) ----------
// (Measured 20-21 us via R18/R19 3x ablation; R17 scalar form.)
__global__ __launch_bounds__(256)
void k_gemm2(const float* __restrict__ W) {
    __shared__ float P_lds[64][68];
    __shared__ float W_lds[64][68];

    const int bm = blockIdx.x;
    const int kc = blockIdx.y;
    const int r0 = bm * 64;
    const int ks = kc * KCHUNK;
    const int ke = (ks + KCHUNK < NST5) ? ks + KCHUNK : NST5;

    const int tid = threadIdx.x;
    const int rg = tid >> 4;
    const int cg = tid & 15;
    const int srow = tid >> 4;
    const int sc4 = (tid & 15) * 4;

    float acc[4][4];
    #pragma unroll
    for (int i = 0; i < 4; i++)
        #pragma unroll
        for (int j = 0; j < 4; j++) acc[i][j] = 0.f;

    for (int k0 = ks; k0 < ke; k0 += 64) {
        const int kw = ke - k0;
        __syncthreads();
        #pragma unroll
        for (int p = 0; p < 4; p++) {
            int row = p * 16 + srow;
            float4 v = make_float4(0.f, 0.f, 0.f, 0.f);
            if (sc4 < kw) {
                const float* src = &g_probs[(size_t)(r0 + row) * NST5 + k0 + sc4];
                if (sc4 + 4 <= kw) {
                    v = *(const float4*)src;
                } else {
                    float tmp[4] = {0.f, 0.f, 0.f, 0.f};
                    for (int i = 0; i < kw - sc4; i++) tmp[i] = src[i];
                    v = *(const float4*)tmp;
                }
            }
            *(float4*)&P_lds[row][sc4] = v;
        }
        #pragma unroll
        for (int p = 0; p < 4; p++) {
            int krow = p * 16 + srow;
            float4 v = make_float4(0.f, 0.f, 0.f, 0.f);
            if (krow < kw)
                v = *(const float4*)&W[(size_t)(k0 + krow) * 64 + sc4];
            *(float4*)&W_lds[krow][sc4] = v;
        }
        __syncthreads();

        #pragma unroll 4
        for (int kk = 0; kk < 64; kk++) {
            float4 wv = *(const float4*)&W_lds[kk][cg * 4];
            float pr[4];
            #pragma unroll
            for (int i = 0; i < 4; i++) pr[i] = P_lds[rg * 4 + i][kk];
            #pragma unroll
            for (int i = 0; i < 4; i++) {
                acc[i][0] = fmaf(pr[i], wv.x, acc[i][0]);
                acc[i][1] = fmaf(pr[i], wv.y, acc[i][1]);
                acc[i][2] = fmaf(pr[i], wv.z, acc[i][2]);
                acc[i][3] = fmaf(pr[i], wv.w, acc[i][3]);
            }
        }
    }

    float* po = g_part + ((size_t)kc * BATCH + r0) * 64;
    #pragma unroll
    for (int i = 0; i < 4; i++) {
        float4 v = make_float4(acc[i][0], acc[i][1], acc[i][2], acc[i][3]);
        *(float4*)&po[(size_t)(rg * 4 + i) * 64 + cg * 4] = v;
    }
}

// ---------- reduce KSPLIT partials + bias ----------
__global__ __launch_bounds__(256)
void k_reduce(const float* __restrict__ bias, float* __restrict__ out) {
    int i = blockIdx.x * 256 + threadIdx.x;
    const int TOT = BATCH * 64;
    if (i < TOT) {
        float v = bias[i & 63];
        #pragma unroll
        for (int m = 0; m < KSPLIT; m++) v += g_part[(size_t)m * TOT + i];
        out[i] = v;
    }
}

extern "C" void kernel_launch(void* const* d_in, const int* in_sizes, int n_in,
                              void* d_out, int out_size, void* d_ws, size_t ws_size,
                              hipStream_t stream) {
    const float* x     = (const float*)d_in[0];
    const float* theta = (const float*)d_in[1];
    const float* W     = (const float*)d_in[2];
    const float* bias  = (const float*)d_in[3];
    float* out = (float*)d_out;
    (void)d_ws; (void)ws_size; (void)in_sizes; (void)n_in; (void)out_size;

    k_setup<<<2, 1024, 0, stream>>>(theta);
    k_slos<<<BATCH / 4, 256, 0, stream>>>(x);
    k_gemm2<<<dim3(64, KSPLIT), 256, 0, stream>>>(W);
    k_reduce<<<1024, 256, 0, stream>>>(bias, out);
}

// Round 21
// 112.908 us; speedup vs baseline: 1.4484x; 1.4484x over previous
//
#include <hip/hip_runtime.h>

#define MODES 10
#define NPH 5
#define DEPTH 10
#define NST5 2002
#define BATCH 4096
#define KSPLIT 16
#define KCHUNK 126

// Factorial-normalized SLOS: b[t] = sum_j U[j,i] b[parent];
// probs[t] = c2[t] * |b5[t]|^2, c2[t] = prod_j t_j! (exact small ints).
// COMPACT tables (10010 edges, no padding), targets bucketed by in-degree d:
//   g_meta[pos] = orig_t | (d<<11) | (rel_edge_off<<14)
//   g_edges[..] = parent_idx | (j<<12), j-ascending per target (fixed order
//   => per-target fmaf sequence fixed => bit-identical, replay-deterministic).
__device__ unsigned g_meta[3002];
__device__ unsigned g_edges[10010];
__device__ int g_cur[25];                // per-(level,degree) bucket cursors
__device__ float g_c2[NST5];
__device__ float2 g_M[MODES][NPH];       // batch-independent mesh matrix cols 0..4
__device__ float g_probs[(size_t)BATCH * NST5];
__device__ float g_part[(size_t)KSPLIT * BATCH * 64];

// ---------- combinatorics ----------
// count(m, n) = C(n+m-1, m-1), m in [1,10], n in [0,5] -> exact constant LUT
// (i64 mul/div loop here once made table-gen take 134 us: soft i64 divide).
__device__ __forceinline__ int d_count(int m, int n) {
    static const unsigned short C[11][6] = {
        {0, 0, 0, 0, 0, 0},
        {1, 1, 1, 1, 1, 1},
        {1, 2, 3, 4, 5, 6},
        {1, 3, 6, 10, 15, 21},
        {1, 4, 10, 20, 35, 56},
        {1, 5, 15, 35, 70, 126},
        {1, 6, 21, 56, 126, 252},
        {1, 7, 28, 84, 210, 462},
        {1, 8, 36, 120, 330, 792},
        {1, 9, 45, 165, 495, 1287},
        {1, 10, 55, 220, 715, 2002},
    };
    return C[m][n];
}

__device__ void d_unrank(int r, int n, int* s) {
    for (int p = 0; p < MODES; p++) {
        int mm = MODES - p;
        if (mm == 1) { s[p] = n; return; }
        int k = n;
        for (; k >= 0; k--) {
            int c = d_count(mm - 1, n - k);
            if (r < c) break;
            r -= c;
        }
        s[p] = k; n -= k;
    }
}

__device__ int d_rank(const int* s, int n) {
    int r = 0;
    for (int p = 0; p < MODES && n > 0; p++) {
        int mm = MODES - p;
        if (mm == 1) break;
        for (int k = n; k > s[p]; k--) r += d_count(mm - 1, n - k);
        n -= s[p];
    }
    return r;
}

// ---------- init: block 0 zeroes bucket cursors, block 1 builds g_M ----------
__global__ __launch_bounds__(256)
void k_init(const float* __restrict__ theta) {
    const int tid = threadIdx.x;
    if (blockIdx.x == 0) {
        if (tid < 25) g_cur[tid] = 0;
        return;
    }
    // mesh matrix M = BS9 D9 ... BS1 D1 BS0 (batch-independent; cols 0..4)
    __shared__ float2 Ush[MODES][NPH];
    const int r = tid / 5, c = tid % 5;
    const bool act = (tid < 50);
    float2 val = make_float2((act && r == c) ? 1.f : 0.f, 0.f);
    for (int l = 0; l < DEPTH; l++) {
        if (act && l > 0) {
            float ang = theta[(l - 1) * MODES + r];
            float s_, c_; sincosf(ang, &s_, &c_);
            float nx = val.x * c_ - val.y * s_;
            float ny = val.x * s_ + val.y * c_;
            val = make_float2(nx, ny);
        }
        if (act) Ush[r][c] = val;
        __syncthreads();
        float2 nv = val;
        if (act) {
            int o = l & 1;
            int lo = r - o;
            int partner = o + (lo ^ 1);
            if (lo >= 0 && partner < MODES) {
                float2 pb = Ush[partner][c];
                const float inv = 0.70710678118654752f;
                nv.x = inv * (val.x - pb.y);
                nv.y = inv * (val.y + pb.x);
            }
        }
        __syncthreads();
        val = nv;
    }
    if (act) g_M[r][c] = val;
}

// ---------- emit compact tables: 12 blocks, 1 item/thread (R13 geometry) ----
// Bucket sizes are STATIC: cnt[k][d] = C(10,d)*C(k,d-1); prefix tables below
// are hardcoded (totals verified: 10/55/220/715/2002 states, 10010 edges).
__global__ __launch_bounds__(256)
void k_emit() {
    int id = blockIdx.x * 256 + threadIdx.x;
    if (id >= 3002) return;
    const int sizes[5] = {10, 55, 220, 715, 2002};
    const int mb[5]    = {0, 10, 65, 285, 1000};        // meta base per level
    const int eb[5]    = {0, 10, 110, 660, 2860};       // edge base per level
    // relative (within-level) bucket starts, index [k][d-1]
    const int basePrel[5][5] = {
        {0, 0, 0, 0, 0},
        {0, 10, 0, 0, 0},
        {0, 10, 100, 0, 0},
        {0, 10, 145, 505, 0},
        {0, 10, 190, 910, 1750},
    };
    const int baseErel[5][5] = {
        {0, 0, 0, 0, 0},
        {0, 10, 0, 0, 0},
        {0, 10, 190, 0, 0},
        {0, 10, 280, 1360, 0},
        {0, 10, 370, 2530, 5890},
    };

    int k = 0, t = id;
    while (k < 5 && t >= sizes[k]) { t -= sizes[k]; k++; }
    int s[10];
    d_unrank(t, k + 1, s);
    int d = 0;
    for (int j = 0; j < MODES; j++) d += (s[j] > 0);

    int slot = atomicAdd(&g_cur[k * 5 + (d - 1)], 1);
    int pos = mb[k] + basePrel[k][d - 1] + slot;
    int eo_rel = baseErel[k][d - 1] + slot * d;
    g_meta[pos] = (unsigned)t | ((unsigned)d << 11) | ((unsigned)eo_rel << 14);

    int w = 0;
    for (int j = 0; j < MODES; j++) {
        if (s[j] > 0) {
            s[j]--;
            int p = d_rank(s, k);
            s[j]++;
            g_edges[eb[k] + eo_rel + w] = (unsigned)p | ((unsigned)j << 12);
            w++;
        }
    }
    if (k == 4) {
        const float fact[6] = {1.f, 1.f, 2.f, 6.f, 24.f, 120.f};
        float c2 = 1.f;
        for (int j = 0; j < MODES; j++) c2 *= fact[s[j]];
        g_c2[t] = c2;
    }
}

// ---------- SLOS level step, compact edges, 4 batch elems packed ----------
__device__ __forceinline__ void slos_lvl(const float4 (*__restrict__ src)[2],
                                         float4 (*__restrict__ dst)[2],
                                         const unsigned* __restrict__ meta,
                                         const unsigned* __restrict__ edges,
                                         int N, int tid,
                                         const float4 (*Ua)[NPH],
                                         const float4 (*Ub)[NPH], int k) {
    for (int pos = tid; pos < N; pos += 256) {
        unsigned m = meta[pos];
        int t = m & 0x7FF;
        int d = (m >> 11) & 0x7;
        const unsigned* ee = edges + (m >> 14);
        float ax0 = 0.f, ay0 = 0.f, ax1 = 0.f, ay1 = 0.f;
        float ax2 = 0.f, ay2 = 0.f, ax3 = 0.f, ay3 = 0.f;
        for (int sl = 0; sl < d; sl++) {
            unsigned e = ee[sl];
            int idx = e & 0xFFF;
            int j = (e >> 12) & 0xF;
            float4 a01 = src[idx][0];
            float4 a23 = src[idx][1];
            float4 u01 = Ua[j][k];
            float4 u23 = Ub[j][k];
            ax0 = fmaf(u01.x, a01.x, ax0); ax0 = fmaf(-u01.y, a01.y, ax0);
            ay0 = fmaf(u01.x, a01.y, ay0); ay0 = fmaf( u01.y, a01.x, ay0);
            ax1 = fmaf(u01.z, a01.z, ax1); ax1 = fmaf(-u01.w, a01.w, ax1);
            ay1 = fmaf(u01.z, a01.w, ay1); ay1 = fmaf( u01.w, a01.z, ay1);
            ax2 = fmaf(u23.x, a23.x, ax2); ax2 = fmaf(-u23.y, a23.y, ax2);
            ay2 = fmaf(u23.x, a23.y, ay2); ay2 = fmaf( u23.y, a23.x, ay2);
            ax3 = fmaf(u23.z, a23.z, ax3); ax3 = fmaf(-u23.w, a23.w, ax3);
            ay3 = fmaf(u23.z, a23.w, ay3); ay3 = fmaf( u23.w, a23.z, ay3);
        }
        dst[t][0] = make_float4(ax0, ay0, ax1, ay1);
        dst[t][1] = make_float4(ax2, ay2, ax3, ay3);
    }
    __syncthreads();
}

// ---------- SLOS, 4 batch elements per block ----------
__global__ __launch_bounds__(256)
void k_slos(const float* __restrict__ x) {
    __shared__ float4 Ua[MODES][NPH];    // (b0.re, b0.im, b1.re, b1.im)
    __shared__ float4 Ub[MODES][NPH];    // (b2.re, b2.im, b3.re, b3.im)
    __shared__ float4 ampA[715][2];
    __shared__ float4 ampB[220][2];

    const int b0 = blockIdx.x * 4;
    const int tid = threadIdx.x;
    const int r = tid / 5, c = tid % 5;

    if (tid < 50) {
        const float TP = 6.28318530717958647692f;
        float s0, c0, s1, c1, s2, c2, s3, c3;
        sincosf(TP * x[(b0 + 0) * MODES + c], &s0, &c0);
        sincosf(TP * x[(b0 + 1) * MODES + c], &s1, &c1);
        sincosf(TP * x[(b0 + 2) * MODES + c], &s2, &c2);
        sincosf(TP * x[(b0 + 3) * MODES + c], &s3, &c3);
        float2 m = g_M[r][c];
        Ua[r][c] = make_float4(m.x * c0 - m.y * s0, m.x * s0 + m.y * c0,
                               m.x * c1 - m.y * s1, m.x * s1 + m.y * c1);
        Ub[r][c] = make_float4(m.x * c2 - m.y * s2, m.x * s2 + m.y * c2,
                               m.x * c3 - m.y * s3, m.x * s3 + m.y * c3);
    }
    if (tid == 0) {
        ampA[0][0] = make_float4(1.f, 0.f, 1.f, 0.f);
        ampA[0][1] = make_float4(1.f, 0.f, 1.f, 0.f);
    }
    __syncthreads();

    slos_lvl(ampA, ampB, g_meta + 0,    g_edges + 0,    10,  tid, Ua, Ub, 0);
    slos_lvl(ampB, ampA, g_meta + 10,   g_edges + 10,   55,  tid, Ua, Ub, 1);
    slos_lvl(ampA, ampB, g_meta + 65,   g_edges + 110,  220, tid, Ua, Ub, 2);
    slos_lvl(ampB, ampA, g_meta + 285,  g_edges + 660,  715, tid, Ua, Ub, 3);

    // level 4 fused with c2 * |.|^2 -> global (no LDS round-trip)
    float* po0 = g_probs + (size_t)b0 * NST5;
    float* po1 = po0 + NST5;
    float* po2 = po1 + NST5;
    float* po3 = po2 + NST5;
    const unsigned* meta = g_meta + 1000;
    const unsigned* edges = g_edges + 2860;
    for (int pos = tid; pos < NST5; pos += 256) {
        unsigned m = meta[pos];
        int t = m & 0x7FF;
        int d = (m >> 11) & 0x7;
        const unsigned* ee = edges + (m >> 14);
        float ax0 = 0.f, ay0 = 0.f, ax1 = 0.f, ay1 = 0.f;
        float ax2 = 0.f, ay2 = 0.f, ax3 = 0.f, ay3 = 0.f;
        for (int sl = 0; sl < d; sl++) {
            unsigned e = ee[sl];
            int idx = e & 0xFFF;
            int j = (e >> 12) & 0xF;
            float4 a01 = ampA[idx][0];
            float4 a23 = ampA[idx][1];
            float4 u01 = Ua[j][4];
            float4 u23 = Ub[j][4];
            ax0 = fmaf(u01.x, a01.x, ax0); ax0 = fmaf(-u01.y, a01.y, ax0);
            ay0 = fmaf(u01.x, a01.y, ay0); ay0 = fmaf( u01.y, a01.x, ay0);
            ax1 = fmaf(u01.z, a01.z, ax1); ax1 = fmaf(-u01.w, a01.w, ax1);
            ay1 = fmaf(u01.z, a01.w, ay1); ay1 = fmaf( u01.w, a01.z, ay1);
            ax2 = fmaf(u23.x, a23.x, ax2); ax2 = fmaf(-u23.y, a23.y, ax2);
            ay2 = fmaf(u23.x, a23.y, ay2); ay2 = fmaf( u23.y, a23.x, ay2);
            ax3 = fmaf(u23.z, a23.z, ax3); ax3 = fmaf(-u23.w, a23.w, ax3);
            ay3 = fmaf(u23.z, a23.w, ay3); ay3 = fmaf( u23.w, a23.z, ay3);
        }
        float c2v = g_c2[t];
        po0[t] = c2v * (ax0 * ax0 + ay0 * ay0);
        po1[t] = c2v * (ax1 * ax1 + ay1 * ay1);
        po2[t] = c2v * (ax2 * ax2 + ay2 * ay2);
        po3[t] = c2v * (ax3 * ax3 + ay3 * ay3);
    }
}

// ---------- GEMM: g_part[kc] = P[64-row tile] x W  (LDS-tiled, K split x16) ----------
// (Measured 20-21 us via R18/R19 3x ablation; R17 scalar form.)
__global__ __launch_bounds__(256)
void k_gemm2(const float* __restrict__ W) {
    __shared__ float P_lds[64][68];
    __shared__ float W_lds[64][68];

    const int bm = blockIdx.x;
    const int kc = blockIdx.y;
    const int r0 = bm * 64;
    const int ks = kc * KCHUNK;
    const int ke = (ks + KCHUNK < NST5) ? ks + KCHUNK : NST5;

    const int tid = threadIdx.x;
    const int rg = tid >> 4;
    const int cg = tid & 15;
    const int srow = tid >> 4;
    const int sc4 = (tid & 15) * 4;

    float acc[4][4];
    #pragma unroll
    for (int i = 0; i < 4; i++)
        #pragma unroll
        for (int j = 0; j < 4; j++) acc[i][j] = 0.f;

    for (int k0 = ks; k0 < ke; k0 += 64) {
        const int kw = ke - k0;
        __syncthreads();
        #pragma unroll
        for (int p = 0; p < 4; p++) {
            int row = p * 16 + srow;
            float4 v = make_float4(0.f, 0.f, 0.f, 0.f);
            if (sc4 < kw) {
                const float* src = &g_probs[(size_t)(r0 + row) * NST5 + k0 + sc4];
                if (sc4 + 4 <= kw) {
                    v = *(const float4*)src;
                } else {
                    float tmp[4] = {0.f, 0.f, 0.f, 0.f};
                    for (int i = 0; i < kw - sc4; i++) tmp[i] = src[i];
                    v = *(const float4*)tmp;
                }
            }
            *(float4*)&P_lds[row][sc4] = v;
        }
        #pragma unroll
        for (int p = 0; p < 4; p++) {
            int krow = p * 16 + srow;
            float4 v = make_float4(0.f, 0.f, 0.f, 0.f);
            if (krow < kw)
                v = *(const float4*)&W[(size_t)(k0 + krow) * 64 + sc4];
            *(float4*)&W_lds[krow][sc4] = v;
        }
        __syncthreads();

        #pragma unroll 4
        for (int kk = 0; kk < 64; kk++) {
            float4 wv = *(const float4*)&W_lds[kk][cg * 4];
            float pr[4];
            #pragma unroll
            for (int i = 0; i < 4; i++) pr[i] = P_lds[rg * 4 + i][kk];
            #pragma unroll
            for (int i = 0; i < 4; i++) {
                acc[i][0] = fmaf(pr[i], wv.x, acc[i][0]);
                acc[i][1] = fmaf(pr[i], wv.y, acc[i][1]);
                acc[i][2] = fmaf(pr[i], wv.z, acc[i][2]);
                acc[i][3] = fmaf(pr[i], wv.w, acc[i][3]);
            }
        }
    }

    float* po = g_part + ((size_t)kc * BATCH + r0) * 64;
    #pragma unroll
    for (int i = 0; i < 4; i++) {
        float4 v = make_float4(acc[i][0], acc[i][1], acc[i][2], acc[i][3]);
        *(float4*)&po[(size_t)(rg * 4 + i) * 64 + cg * 4] = v;
    }
}

// ---------- reduce KSPLIT partials + bias ----------
__global__ __launch_bounds__(256)
void k_reduce(const float* __restrict__ bias, float* __restrict__ out) {
    int i = blockIdx.x * 256 + threadIdx.x;
    const int TOT = BATCH * 64;
    if (i < TOT) {
        float v = bias[i & 63];
        #pragma unroll
        for (int m = 0; m < KSPLIT; m++) v += g_part[(size_t)m * TOT + i];
        out[i] = v;
    }
}

extern "C" void kernel_launch(void* const* d_in, const int* in_sizes, int n_in,
                              void* d_out, int out_size, void* d_ws, size_t ws_size,
                              hipStream_t stream) {
    const float* x     = (const float*)d_in[0];
    const float* theta = (const float*)d_in[1];
    const float* W     = (const float*)d_in[2];
    const float* bias  = (const float*)d_in[3];
    float* out = (float*)d_out;
    (void)d_ws; (void)ws_size; (void)in_sizes; (void)n_in; (void)out_size;

    k_init<<<2, 256, 0, stream>>>(theta);
    k_emit<<<12, 256, 0, stream>>>();
    k_slos<<<BATCH / 4, 256, 0, stream>>>(x);
    k_gemm2<<<dim3(64, KSPLIT), 256, 0, stream>>>(W);
    k_reduce<<<1024, 256, 0, stream>>>(bias, out);
}

// Round 22
// 62.784 us; speedup vs baseline: 2.6047x; 1.7983x over previous
//
#include <hip/hip_runtime.h>

#define MODES 10
#define NPH 5
#define DEPTH 10
#define NST5 2002
#define BATCH 4096
#define KSPLIT 16
#define KCHUNK 126

// ============ COMPILE-TIME transition tables ============
// Everything in g_T is input-independent, so it is built by a constexpr
// generator at COMPILE time (runtime table-gen measured 35-50 us across
// R13-R21: serial dependent-LUT unrank/rank chains at 0.3% VALUBusy).
// Layout identical to R21's runtime version (degree-bucketed compact CSR;
// within-bucket t-ascending, edges j-ascending => bit-identical results):
//   meta[pos]  = t | (d<<11) | (rel_edge_off<<14)   (per level, base mb[k])
//   edges[..]  = parent_idx | (j<<12)               (per level, base eb[k])
//   c2[t]      = prod_j t_j!  (exact small ints in float)
struct DevTables {
    unsigned meta[3002];
    unsigned edges[10010];
    float c2[NST5];
};

constexpr DevTables build_tables() {
    DevTables T{};
    const int sizes[6] = {1, 10, 55, 220, 715, 2002};
    const int mb[5] = {0, 10, 65, 285, 1000};
    const int eb[5] = {0, 10, 110, 660, 2860};
    const float fact[6] = {1.f, 1.f, 2.f, 6.f, 24.f, 120.f};

    unsigned prev[715] = {};   // packed states of previous level (descending)
    unsigned cur[2002] = {};
    int dd[2002] = {};
    int s[10] = {};
    int prevN = 1;
    prev[0] = 0u;              // vacuum

    for (int lvl = 1; lvl <= 5; ++lvl) {
        const int k = lvl - 1;
        const int N = sizes[lvl];

        // ---- pass 1: enumerate (odometer), pack, degree, bucket counts ----
        int cnt[5] = {0, 0, 0, 0, 0};
        for (int p = 0; p < 10; ++p) s[p] = 0;
        s[0] = lvl;
        for (int t = 0; t < N; ++t) {
            unsigned P = 0;
            int d = 0;
            for (int p = 0; p < 10; ++p) {
                P |= (unsigned)s[p] << (3 * (9 - p));
                d += (s[p] > 0) ? 1 : 0;
            }
            cur[t] = P;
            dd[t] = d;
            cnt[d - 1] += 1;
            int p = 8;                       // advance odometer
            while (p >= 0 && s[p] == 0) --p;
            if (p >= 0) {
                int rest = 1;
                for (int q = p + 1; q < 10; ++q) { rest += s[q]; s[q] = 0; }
                s[p] -= 1;
                s[p + 1] = rest;
            }
        }
        // ---- bucket prefix (relative within level) ----
        int bp[5] = {}, be[5] = {};
        {
            int pp = 0, ee = 0;
            for (int d = 0; d < 5; ++d) {
                bp[d] = pp; be[d] = ee;
                pp += cnt[d]; ee += cnt[d] * (d + 1);
            }
        }
        // ---- pass 2: emit meta/edges (binary-search parents) ----
        for (int p = 0; p < 10; ++p) s[p] = 0;
        s[0] = lvl;
        for (int t = 0; t < N; ++t) {
            const int d = dd[t];
            const int pos = mb[k] + bp[d - 1];
            const int eo = be[d - 1];
            bp[d - 1] += 1;
            be[d - 1] += d;
            T.meta[pos] = (unsigned)t | ((unsigned)d << 11) | ((unsigned)eo << 14);
            int w = 0;
            for (int j = 0; j < 10; ++j) {
                if (s[j] > 0) {
                    unsigned pp2 = cur[t] - (1u << (3 * (9 - j)));
                    int lo = 0, hi = prevN - 1;   // prev[] strictly descending
                    while (lo < hi) {
                        int mid = (lo + hi) >> 1;
                        if (prev[mid] > pp2) lo = mid + 1; else hi = mid;
                    }
                    T.edges[eb[k] + eo + w] = (unsigned)lo | ((unsigned)j << 12);
                    w += 1;
                }
            }
            if (lvl == 5) {
                float c2 = 1.f;
                for (int j = 0; j < 10; ++j) c2 *= fact[s[j]];
                T.c2[t] = c2;
            }
            int p = 8;                       // advance odometer
            while (p >= 0 && s[p] == 0) --p;
            if (p >= 0) {
                int rest = 1;
                for (int q = p + 1; q < 10; ++q) { rest += s[q]; s[q] = 0; }
                s[p] -= 1;
                s[p + 1] = rest;
            }
        }
        if (lvl < 5) {
            for (int t = 0; t < N; ++t) prev[t] = cur[t];
            prevN = N;
        }
    }
    return T;
}

__device__ const DevTables g_T = build_tables();

// ---------- runtime scratch ----------
__device__ float2 g_M[MODES][NPH];       // batch-independent mesh matrix cols 0..4
__device__ float g_probs[(size_t)BATCH * NST5];
__device__ float g_part[(size_t)KSPLIT * BATCH * 64];

// ---------- init: build g_M = BS9 D9 ... BS1 D1 BS0 (cols 0..4) ----------
__global__ __launch_bounds__(64)
void k_init(const float* __restrict__ theta) {
    __shared__ float2 Ush[MODES][NPH];
    const int tid = threadIdx.x;
    const int r = tid / 5, c = tid % 5;
    const bool act = (tid < 50);
    float2 val = make_float2((act && r == c) ? 1.f : 0.f, 0.f);
    for (int l = 0; l < DEPTH; l++) {
        if (act && l > 0) {
            float ang = theta[(l - 1) * MODES + r];
            float s_, c_; sincosf(ang, &s_, &c_);
            float nx = val.x * c_ - val.y * s_;
            float ny = val.x * s_ + val.y * c_;
            val = make_float2(nx, ny);
        }
        if (act) Ush[r][c] = val;
        __syncthreads();
        float2 nv = val;
        if (act) {
            int o = l & 1;
            int lo = r - o;
            int partner = o + (lo ^ 1);
            if (lo >= 0 && partner < MODES) {
                float2 pb = Ush[partner][c];
                const float inv = 0.70710678118654752f;
                nv.x = inv * (val.x - pb.y);
                nv.y = inv * (val.y + pb.x);
            }
        }
        __syncthreads();
        val = nv;
    }
    if (act) g_M[r][c] = val;
}

// ---------- SLOS level step, compact edges, 4 batch elems packed ----------
__device__ __forceinline__ void slos_lvl(const float4 (*__restrict__ src)[2],
                                         float4 (*__restrict__ dst)[2],
                                         const unsigned* __restrict__ meta,
                                         const unsigned* __restrict__ edges,
                                         int N, int tid,
                                         const float4 (*Ua)[NPH],
                                         const float4 (*Ub)[NPH], int k) {
    for (int pos = tid; pos < N; pos += 256) {
        unsigned m = meta[pos];
        int t = m & 0x7FF;
        int d = (m >> 11) & 0x7;
        const unsigned* ee = edges + (m >> 14);
        float ax0 = 0.f, ay0 = 0.f, ax1 = 0.f, ay1 = 0.f;
        float ax2 = 0.f, ay2 = 0.f, ax3 = 0.f, ay3 = 0.f;
        for (int sl = 0; sl < d; sl++) {
            unsigned e = ee[sl];
            int idx = e & 0xFFF;
            int j = (e >> 12) & 0xF;
            float4 a01 = src[idx][0];
            float4 a23 = src[idx][1];
            float4 u01 = Ua[j][k];
            float4 u23 = Ub[j][k];
            ax0 = fmaf(u01.x, a01.x, ax0); ax0 = fmaf(-u01.y, a01.y, ax0);
            ay0 = fmaf(u01.x, a01.y, ay0); ay0 = fmaf( u01.y, a01.x, ay0);
            ax1 = fmaf(u01.z, a01.z, ax1); ax1 = fmaf(-u01.w, a01.w, ax1);
            ay1 = fmaf(u01.z, a01.w, ay1); ay1 = fmaf( u01.w, a01.z, ay1);
            ax2 = fmaf(u23.x, a23.x, ax2); ax2 = fmaf(-u23.y, a23.y, ax2);
            ay2 = fmaf(u23.x, a23.y, ay2); ay2 = fmaf( u23.y, a23.x, ay2);
            ax3 = fmaf(u23.z, a23.z, ax3); ax3 = fmaf(-u23.w, a23.w, ax3);
            ay3 = fmaf(u23.z, a23.w, ay3); ay3 = fmaf( u23.w, a23.z, ay3);
        }
        dst[t][0] = make_float4(ax0, ay0, ax1, ay1);
        dst[t][1] = make_float4(ax2, ay2, ax3, ay3);
    }
    __syncthreads();
}

// ---------- SLOS, 4 batch elements per block ----------
__global__ __launch_bounds__(256)
void k_slos(const float* __restrict__ x) {
    __shared__ float4 Ua[MODES][NPH];    // (b0.re, b0.im, b1.re, b1.im)
    __shared__ float4 Ub[MODES][NPH];    // (b2.re, b2.im, b3.re, b3.im)
    __shared__ float4 ampA[715][2];
    __shared__ float4 ampB[220][2];

    const int b0 = blockIdx.x * 4;
    const int tid = threadIdx.x;
    const int r = tid / 5, c = tid % 5;

    if (tid < 50) {
        const float TP = 6.28318530717958647692f;
        float s0, c0, s1, c1, s2, c2, s3, c3;
        sincosf(TP * x[(b0 + 0) * MODES + c], &s0, &c0);
        sincosf(TP * x[(b0 + 1) * MODES + c], &s1, &c1);
        sincosf(TP * x[(b0 + 2) * MODES + c], &s2, &c2);
        sincosf(TP * x[(b0 + 3) * MODES + c], &s3, &c3);
        float2 m = g_M[r][c];
        Ua[r][c] = make_float4(m.x * c0 - m.y * s0, m.x * s0 + m.y * c0,
                               m.x * c1 - m.y * s1, m.x * s1 + m.y * c1);
        Ub[r][c] = make_float4(m.x * c2 - m.y * s2, m.x * s2 + m.y * c2,
                               m.x * c3 - m.y * s3, m.x * s3 + m.y * c3);
    }
    if (tid == 0) {
        ampA[0][0] = make_float4(1.f, 0.f, 1.f, 0.f);
        ampA[0][1] = make_float4(1.f, 0.f, 1.f, 0.f);
    }
    __syncthreads();

    slos_lvl(ampA, ampB, g_T.meta + 0,   g_T.edges + 0,    10,  tid, Ua, Ub, 0);
    slos_lvl(ampB, ampA, g_T.meta + 10,  g_T.edges + 10,   55,  tid, Ua, Ub, 1);
    slos_lvl(ampA, ampB, g_T.meta + 65,  g_T.edges + 110,  220, tid, Ua, Ub, 2);
    slos_lvl(ampB, ampA, g_T.meta + 285, g_T.edges + 660,  715, tid, Ua, Ub, 3);

    // level 4 fused with c2 * |.|^2 -> global (no LDS round-trip)
    float* po0 = g_probs + (size_t)b0 * NST5;
    float* po1 = po0 + NST5;
    float* po2 = po1 + NST5;
    float* po3 = po2 + NST5;
    const unsigned* meta = g_T.meta + 1000;
    const unsigned* edges = g_T.edges + 2860;
    for (int pos = tid; pos < NST5; pos += 256) {
        unsigned m = meta[pos];
        int t = m & 0x7FF;
        int d = (m >> 11) & 0x7;
        const unsigned* ee = edges + (m >> 14);
        float ax0 = 0.f, ay0 = 0.f, ax1 = 0.f, ay1 = 0.f;
        float ax2 = 0.f, ay2 = 0.f, ax3 = 0.f, ay3 = 0.f;
        for (int sl = 0; sl < d; sl++) {
            unsigned e = ee[sl];
            int idx = e & 0xFFF;
            int j = (e >> 12) & 0xF;
            float4 a01 = ampA[idx][0];
            float4 a23 = ampA[idx][1];
            float4 u01 = Ua[j][4];
            float4 u23 = Ub[j][4];
            ax0 = fmaf(u01.x, a01.x, ax0); ax0 = fmaf(-u01.y, a01.y, ax0);
            ay0 = fmaf(u01.x, a01.y, ay0); ay0 = fmaf( u01.y, a01.x, ay0);
            ax1 = fmaf(u01.z, a01.z, ax1); ax1 = fmaf(-u01.w, a01.w, ax1);
            ay1 = fmaf(u01.z, a01.w, ay1); ay1 = fmaf( u01.w, a01.z, ay1);
            ax2 = fmaf(u23.x, a23.x, ax2); ax2 = fmaf(-u23.y, a23.y, ax2);
            ay2 = fmaf(u23.x, a23.y, ay2); ay2 = fmaf( u23.y, a23.x, ay2);
            ax3 = fmaf(u23.z, a23.z, ax3); ax3 = fmaf(-u23.w, a23.w, ax3);
            ay3 = fmaf(u23.z, a23.w, ay3); ay3 = fmaf( u23.w, a23.z, ay3);
        }
        float c2v = g_T.c2[t];
        po0[t] = c2v * (ax0 * ax0 + ay0 * ay0);
        po1[t] = c2v * (ax1 * ax1 + ay1 * ay1);
        po2[t] = c2v * (ax2 * ax2 + ay2 * ay2);
        po3[t] = c2v * (ax3 * ax3 + ay3 * ay3);
    }
}

// ---------- GEMM: g_part[kc] = P[64-row tile] x W  (LDS-tiled, K split x16) ----------
// (Measured 20-21 us via R18/R19 3x ablation; R17 scalar form.)
__global__ __launch_bounds__(256)
void k_gemm2(const float* __restrict__ W) {
    __shared__ float P_lds[64][68];
    __shared__ float W_lds[64][68];

    const int bm = blockIdx.x;
    const int kc = blockIdx.y;
    const int r0 = bm * 64;
    const int ks = kc * KCHUNK;
    const int ke = (ks + KCHUNK < NST5) ? ks + KCHUNK : NST5;

    const int tid = threadIdx.x;
    const int rg = tid >> 4;
    const int cg = tid & 15;
    const int srow = tid >> 4;
    const int sc4 = (tid & 15) * 4;

    float acc[4][4];
    #pragma unroll
    for (int i = 0; i < 4; i++)
        #pragma unroll
        for (int j = 0; j < 4; j++) acc[i][j] = 0.f;

    for (int k0 = ks; k0 < ke; k0 += 64) {
        const int kw = ke - k0;
        __syncthreads();
        #pragma unroll
        for (int p = 0; p < 4; p++) {
            int row = p * 16 + srow;
            float4 v = make_float4(0.f, 0.f, 0.f, 0.f);
            if (sc4 < kw) {
                const float* src = &g_probs[(size_t)(r0 + row) * NST5 + k0 + sc4];
                if (sc4 + 4 <= kw) {
                    v = *(const float4*)src;
                } else {
                    float tmp[4] = {0.f, 0.f, 0.f, 0.f};
                    for (int i = 0; i < kw - sc4; i++) tmp[i] = src[i];
                    v = *(const float4*)tmp;
                }
            }
            *(float4*)&P_lds[row][sc4] = v;
        }
        #pragma unroll
        for (int p = 0; p < 4; p++) {
            int krow = p * 16 + srow;
            float4 v = make_float4(0.f, 0.f, 0.f, 0.f);
            if (krow < kw)
                v = *(const float4*)&W[(size_t)(k0 + krow) * 64 + sc4];
            *(float4*)&W_lds[krow][sc4] = v;
        }
        __syncthreads();

        #pragma unroll 4
        for (int kk = 0; kk < 64; kk++) {
            float4 wv = *(const float4*)&W_lds[kk][cg * 4];
            float pr[4];
            #pragma unroll
            for (int i = 0; i < 4; i++) pr[i] = P_lds[rg * 4 + i][kk];
            #pragma unroll
            for (int i = 0; i < 4; i++) {
                acc[i][0] = fmaf(pr[i], wv.x, acc[i][0]);
                acc[i][1] = fmaf(pr[i], wv.y, acc[i][1]);
                acc[i][2] = fmaf(pr[i], wv.z, acc[i][2]);
                acc[i][3] = fmaf(pr[i], wv.w, acc[i][3]);
            }
        }
    }

    float* po = g_part + ((size_t)kc * BATCH + r0) * 64;
    #pragma unroll
    for (int i = 0; i < 4; i++) {
        float4 v = make_float4(acc[i][0], acc[i][1], acc[i][2], acc[i][3]);
        *(float4*)&po[(size_t)(rg * 4 + i) * 64 + cg * 4] = v;
    }
}

// ---------- reduce KSPLIT partials + bias ----------
__global__ __launch_bounds__(256)
void k_reduce(const float* __restrict__ bias, float* __restrict__ out) {
    int i = blockIdx.x * 256 + threadIdx.x;
    const int TOT = BATCH * 64;
    if (i < TOT) {
        float v = bias[i & 63];
        #pragma unroll
        for (int m = 0; m < KSPLIT; m++) v += g_part[(size_t)m * TOT + i];
        out[i] = v;
    }
}

extern "C" void kernel_launch(void* const* d_in, const int* in_sizes, int n_in,
                              void* d_out, int out_size, void* d_ws, size_t ws_size,
                              hipStream_t stream) {
    const float* x     = (const float*)d_in[0];
    const float* theta = (const float*)d_in[1];
    const float* W     = (const float*)d_in[2];
    const float* bias  = (const float*)d_in[3];
    float* out = (float*)d_out;
    (void)d_ws; (void)ws_size; (void)in_sizes; (void)n_in; (void)out_size;

    k_init<<<1, 64, 0, stream>>>(theta);
    k_slos<<<BATCH / 4, 256, 0, stream>>>(x);
    k_gemm2<<<dim3(64, KSPLIT), 256, 0, stream>>>(W);
    k_reduce<<<1024, 256, 0, stream>>>(bias, out);
}